// Round 2
// baseline (458.138 us; speedup 1.0000x reference)
//
#include <hip/hip_runtime.h>

typedef unsigned short u16;
typedef __bf16 bf16x8 __attribute__((ext_vector_type(8)));
typedef float f32x4 __attribute__((ext_vector_type(4)));
typedef unsigned short u16x4 __attribute__((ext_vector_type(4)));

__device__ __forceinline__ u16 f2bf(float f) {
    union { float f; unsigned int u; } a; a.f = f;
    unsigned int u = a.u;
    u += 0x7FFFu + ((u >> 16) & 1u);   // round-to-nearest-even (finite inputs)
    return (u16)(u >> 16);
}
__device__ __forceinline__ bf16x8 ldg8(const u16* p) {
    return *reinterpret_cast<const bf16x8*>(p);
}

#define MFMA16(a, b, c) __builtin_amdgcn_mfma_f32_16x16x32_bf16((a), (b), (c), 0, 0, 0)

// ---------------------------------------------------------------------------
// Convert a row-major fp32 matrix to bf16 (same layout). n must be %4 == 0.
// ---------------------------------------------------------------------------
__global__ __launch_bounds__(256) void pack_bf16(const float* __restrict__ src,
                                                 u16* __restrict__ dst, int n4) {
    int i = blockIdx.x * 256 + threadIdx.x;
    if (i >= n4) return;
    const float4 v = reinterpret_cast<const float4*>(src)[i];
    u16x4 o;
    o[0] = f2bf(v.x); o[1] = f2bf(v.y); o[2] = f2bf(v.z); o[3] = f2bf(v.w);
    reinterpret_cast<u16x4*>(dst)[i] = o;
}

// ---------------------------------------------------------------------------
// Transpose X (512 x 4096 fp32 channel-major) -> Xt (4096 x 512 bf16 token-major)
// ---------------------------------------------------------------------------
__global__ __launch_bounds__(256) void transpose_ct(const float* __restrict__ X,
                                                    u16* __restrict__ Xt) {
    __shared__ u16 tile[64][65];
    const int tid = threadIdx.x;
    const int t0 = blockIdx.x * 64;   // token tile
    const int c0 = blockIdx.y * 64;   // channel tile
#pragma unroll
    for (int i = 0; i < 16; ++i) {
        int idx = tid + i * 256;
        int r = idx >> 6, cc = idx & 63;
        tile[r][cc] = f2bf(X[(size_t)(c0 + r) * 4096 + t0 + cc]);
    }
    __syncthreads();
#pragma unroll
    for (int i = 0; i < 16; ++i) {
        int idx = tid + i * 256;
        int tr = idx >> 6, cc = idx & 63;
        Xt[(size_t)(t0 + tr) * 512 + c0 + cc] = tile[cc][tr];
    }
}

// ---------------------------------------------------------------------------
// GEMM: val[o][t] = (sum_i W[o][i] * Bt[t][i] + bias[o]) * scale
// W: 512x512 bf16 row-major.  Bt: 4096x512 bf16 token-major.
// mode 0: bf16 out[t*512 + o]   (token-major: Qt, Kt)
// mode 1: bf16 out[o*4096 + t]  (channel-major: Vc)
// mode 2: fp32 out[o*4096 + t]  (final Y -> d_out)
// ---------------------------------------------------------------------------
__global__ __launch_bounds__(256) void proj_gemm(const u16* __restrict__ W,
                                                 const u16* __restrict__ Bt,
                                                 const float* __restrict__ bias,
                                                 void* __restrict__ outp,
                                                 int mode, float scale) {
    const int tid = threadIdx.x;
    const int w = tid >> 6, lane = tid & 63;
    const int quad = lane >> 4, lm = lane & 15;
    const int t0 = blockIdx.x * 64;
    const int o0 = blockIdx.y * 64;
    const int ow = o0 + w * 16;

    f32x4 acc[4];
#pragma unroll
    for (int nt = 0; nt < 4; ++nt) acc[nt] = (f32x4){0.f, 0.f, 0.f, 0.f};

    const u16* arow = W + (size_t)(ow + lm) * 512 + quad * 8;
    const u16* brow = Bt + (size_t)(t0 + lm) * 512 + quad * 8;

    for (int kc = 0; kc < 16; ++kc) {          // K = 512 = 16 * 32
        bf16x8 a = ldg8(arow + kc * 32);
#pragma unroll
        for (int nt = 0; nt < 4; ++nt) {
            bf16x8 b = ldg8(brow + (size_t)nt * 16 * 512 + kc * 32);
            acc[nt] = MFMA16(a, b, acc[nt]);
        }
    }

    const int ob = ow + quad * 4;              // output row base for this lane's regs
    float bv[4];
#pragma unroll
    for (int r = 0; r < 4; ++r) bv[r] = bias[ob + r];

    if (mode == 0) {                            // token-major bf16
        u16* out = (u16*)outp;
#pragma unroll
        for (int nt = 0; nt < 4; ++nt) {
            u16x4 pk;
#pragma unroll
            for (int r = 0; r < 4; ++r) pk[r] = f2bf((acc[nt][r] + bv[r]) * scale);
            *reinterpret_cast<u16x4*>(out + (size_t)(t0 + nt * 16 + lm) * 512 + ob) = pk;
        }
    } else if (mode == 1) {                     // channel-major bf16
        u16* out = (u16*)outp;
#pragma unroll
        for (int nt = 0; nt < 4; ++nt)
#pragma unroll
            for (int r = 0; r < 4; ++r)
                out[(size_t)(ob + r) * 4096 + t0 + nt * 16 + lm] =
                    f2bf((acc[nt][r] + bv[r]) * scale);
    } else {                                    // channel-major fp32 (final output)
        float* out = (float*)outp;
#pragma unroll
        for (int nt = 0; nt < 4; ++nt)
#pragma unroll
            for (int r = 0; r < 4; ++r)
                out[(size_t)(ob + r) * 4096 + t0 + nt * 16 + lm] =
                    (acc[nt][r] + bv[r]) * scale;
    }
}

// ---------------------------------------------------------------------------
// Flash attention. Qt/Kt: 4096x512 bf16 token-major (softmax scale folded into Qt).
// Vc: 512x4096 bf16 channel-major. lqw: 4096 fp32 additive key bias.
// Ot: 4096x512 bf16 token-major output.
// Grid: (64 q-tiles, 8 heads), 256 threads. Wave w owns q-rows [qt0+16w, +16).
// ---------------------------------------------------------------------------
__global__ __launch_bounds__(256) void flash_attn(const u16* __restrict__ Qt,
                                                  const u16* __restrict__ Kt,
                                                  const u16* __restrict__ Vc,
                                                  const float* __restrict__ lqw,
                                                  u16* __restrict__ Ot) {
    __shared__ u16 Pbuf[4][16][80];   // per-wave P tile, stride 80 (16B-aligned rows)

    const int tid = threadIdx.x;
    const int w = tid >> 6, lane = tid & 63;
    const int quad = lane >> 4, lm = lane & 15;
    const int h = blockIdx.y;
    const int qt0 = blockIdx.x * 64;
    const int qrow = qt0 + w * 16;

    // Q A-fragments for this wave's 16 rows, d = 64 -> two k-steps, kept in regs
    const u16* qbase = Qt + (size_t)(qrow + lm) * 512 + h * 64 + quad * 8;
    const bf16x8 a_q0 = ldg8(qbase);
    const bf16x8 a_q1 = ldg8(qbase + 32);

    f32x4 acc_o[4];
#pragma unroll
    for (int nt = 0; nt < 4; ++nt) acc_o[nt] = (f32x4){0.f, 0.f, 0.f, 0.f};
    float m_st[4] = {-1e30f, -1e30f, -1e30f, -1e30f};
    float l_st[4] = {0.f, 0.f, 0.f, 0.f};

    for (int kt0 = 0; kt0 < 4096; kt0 += 64) {
        // --- S = Q K^T (+ key bias), 16x64 per wave ---
        f32x4 s[4];
#pragma unroll
        for (int nt = 0; nt < 4; ++nt) {
            const u16* kb = Kt + (size_t)(kt0 + nt * 16 + lm) * 512 + h * 64 + quad * 8;
            f32x4 a = (f32x4){0.f, 0.f, 0.f, 0.f};
            a = MFMA16(a_q0, ldg8(kb), a);
            a = MFMA16(a_q1, ldg8(kb + 32), a);
            float lw = lqw[kt0 + nt * 16 + lm];   // per-key additive bias (col)
#pragma unroll
            for (int r = 0; r < 4; ++r) s[nt][r] = a[r] + lw;
        }

        // --- online softmax (rows quad*4+r, reduce across the 16 lanes of quad) ---
#pragma unroll
        for (int r = 0; r < 4; ++r) {
            float mx = fmaxf(fmaxf(s[0][r], s[1][r]), fmaxf(s[2][r], s[3][r]));
            mx = fmaxf(mx, __shfl_xor(mx, 1, 64));
            mx = fmaxf(mx, __shfl_xor(mx, 2, 64));
            mx = fmaxf(mx, __shfl_xor(mx, 4, 64));
            mx = fmaxf(mx, __shfl_xor(mx, 8, 64));
            float mnew = fmaxf(m_st[r], mx);
            float alpha = __expf(m_st[r] - mnew);
            m_st[r] = mnew;
            float ps = 0.f;
#pragma unroll
            for (int nt = 0; nt < 4; ++nt) {
                float p = __expf(s[nt][r] - mnew);
                s[nt][r] = p;
                ps += p;
            }
            ps += __shfl_xor(ps, 1, 64);
            ps += __shfl_xor(ps, 2, 64);
            ps += __shfl_xor(ps, 4, 64);
            ps += __shfl_xor(ps, 8, 64);
            l_st[r] = l_st[r] * alpha + ps;
#pragma unroll
            for (int nt = 0; nt < 4; ++nt) acc_o[nt][r] *= alpha;
        }

        // --- P (C-layout regs) -> LDS row-major A-layout tile (wave-private) ---
#pragma unroll
        for (int nt = 0; nt < 4; ++nt)
#pragma unroll
            for (int r = 0; r < 4; ++r)
                Pbuf[w][quad * 4 + r][nt * 16 + lm] = f2bf(s[nt][r]);
        __syncthreads();

        // --- O += P V ---
        bf16x8 ap0 = *reinterpret_cast<const bf16x8*>(&Pbuf[w][lm][quad * 8]);
        bf16x8 ap1 = *reinterpret_cast<const bf16x8*>(&Pbuf[w][lm][32 + quad * 8]);
#pragma unroll
        for (int nt = 0; nt < 4; ++nt) {
            const u16* vb = Vc + (size_t)(h * 64 + nt * 16 + lm) * 4096 + kt0 + quad * 8;
            acc_o[nt] = MFMA16(ap0, ldg8(vb), acc_o[nt]);
            acc_o[nt] = MFMA16(ap1, ldg8(vb + 32), acc_o[nt]);
        }
    }

    // --- epilogue: normalize, store token-major bf16 ---
    float inv[4];
#pragma unroll
    for (int r = 0; r < 4; ++r) inv[r] = 1.0f / l_st[r];
#pragma unroll
    for (int nt = 0; nt < 4; ++nt)
#pragma unroll
        for (int r = 0; r < 4; ++r)
            Ot[(size_t)(qrow + quad * 4 + r) * 512 + h * 64 + nt * 16 + lm] =
                f2bf(acc_o[nt][r] * inv[r]);
}

// ---------------------------------------------------------------------------
extern "C" void kernel_launch(void* const* d_in, const int* in_sizes, int n_in,
                              void* d_out, int out_size, void* d_ws, size_t ws_size,
                              hipStream_t stream) {
    (void)in_sizes; (void)n_in; (void)out_size; (void)ws_size;
    const float* X   = (const float*)d_in[0];
    const float* qw  = (const float*)d_in[1];
    const float* qb  = (const float*)d_in[2];
    const float* kw  = (const float*)d_in[3];
    const float* kb  = (const float*)d_in[4];
    const float* vw  = (const float*)d_in[5];
    const float* vb  = (const float*)d_in[6];
    const float* pw  = (const float*)d_in[7];
    const float* pb  = (const float*)d_in[8];
    const float* lqw = (const float*)d_in[9];

    const size_t E = (size_t)4096 * 512;   // activation elements
    const size_t WE = (size_t)512 * 512;   // weight elements
    u16* Xt  = (u16*)d_ws;     // 4 MB
    u16* Qt  = Xt + E;         // 4 MB
    u16* Kt  = Qt + E;         // 4 MB
    u16* Vc  = Kt + E;         // 4 MB
    u16* Wq  = Vc + E;         // 512 KB
    u16* Wk  = Wq + WE;        // 512 KB
    u16* Wv  = Wk + WE;        // 512 KB
    u16* Wp  = Wv + WE;        // 512 KB
    u16* Ot  = Xt;             // reuse Xt region (dead after projections)

    dim3 blk(256);
    transpose_ct<<<dim3(64, 8), blk, 0, stream>>>(X, Xt);
    pack_bf16<<<dim3(256), blk, 0, stream>>>(qw, Wq, (int)(WE / 4));
    pack_bf16<<<dim3(256), blk, 0, stream>>>(kw, Wk, (int)(WE / 4));
    pack_bf16<<<dim3(256), blk, 0, stream>>>(vw, Wv, (int)(WE / 4));
    pack_bf16<<<dim3(256), blk, 0, stream>>>(pw, Wp, (int)(WE / 4));
    // softmax scale 1/sqrt(64)=0.125 folded into Q (applied after bias, matching ref)
    proj_gemm<<<dim3(64, 8), blk, 0, stream>>>(Wq, Xt, qb, Qt, 0, 0.125f);
    proj_gemm<<<dim3(64, 8), blk, 0, stream>>>(Wk, Xt, kb, Kt, 0, 1.0f);
    proj_gemm<<<dim3(64, 8), blk, 0, stream>>>(Wv, Xt, vb, Vc, 1, 1.0f);
    flash_attn<<<dim3(64, 8), blk, 0, stream>>>(Qt, Kt, Vc, lqw, Ot);
    proj_gemm<<<dim3(64, 8), blk, 0, stream>>>(Wp, Ot, pb, d_out, 2, 1.0f);
}

// Round 3
// 402.096 us; speedup vs baseline: 1.1394x; 1.1394x over previous
//
#include <hip/hip_runtime.h>

typedef unsigned short u16;
typedef unsigned int u32;
typedef __bf16 bf16x8 __attribute__((ext_vector_type(8)));
typedef float f32x4 __attribute__((ext_vector_type(4)));
typedef unsigned short u16x4 __attribute__((ext_vector_type(4)));

#define LOG2E 1.4426950408889634f

#if __has_builtin(__builtin_amdgcn_exp2f)
#define EXP2F(x) __builtin_amdgcn_exp2f(x)
#else
#define EXP2F(x) exp2f(x)
#endif

__device__ __forceinline__ u16 f2bf(float f) {
    union { float f; u32 u; } a; a.f = f;
    u32 u = a.u;
    u += 0x7FFFu + ((u >> 16) & 1u);   // RNE (finite inputs)
    return (u16)(u >> 16);
}
__device__ __forceinline__ bf16x8 ldg8(const u16* p) {
    return *reinterpret_cast<const bf16x8*>(p);
}
// pack two fp32 -> two bf16 (round-half-up) in one v_perm
__device__ __forceinline__ u32 pack_bf2(float a, float b) {
    u32 ua = __float_as_uint(a) + 0x8000u;
    u32 ub = __float_as_uint(b) + 0x8000u;
    return __builtin_amdgcn_perm(ub, ua, 0x07060302);
}

#define MFMA16(a, b, c) __builtin_amdgcn_mfma_f32_16x16x32_bf16((a), (b), (c), 0, 0, 0)

// ---------------------------------------------------------------------------
// Pack the four 512x512 fp32 weight matrices to bf16 in one dispatch.
// ---------------------------------------------------------------------------
__global__ __launch_bounds__(256) void pack4(const float* __restrict__ s0, u16* __restrict__ d0,
                                             const float* __restrict__ s1, u16* __restrict__ d1,
                                             const float* __restrict__ s2, u16* __restrict__ d2,
                                             const float* __restrict__ s3, u16* __restrict__ d3) {
    const float* s; u16* d;
    switch (blockIdx.y) {
        case 0: s = s0; d = d0; break;
        case 1: s = s1; d = d1; break;
        case 2: s = s2; d = d2; break;
        default: s = s3; d = d3; break;
    }
    int i = blockIdx.x * 256 + threadIdx.x;          // 256*256 = 65536 float4s
    float4 v = reinterpret_cast<const float4*>(s)[i];
    u16x4 o;
    o[0] = f2bf(v.x); o[1] = f2bf(v.y); o[2] = f2bf(v.z); o[3] = f2bf(v.w);
    reinterpret_cast<u16x4*>(d)[i] = o;
}

// ---------------------------------------------------------------------------
// Transpose X (512 x 4096 fp32 channel-major) -> Xt (4096 x 512 bf16 token-major)
// ---------------------------------------------------------------------------
__global__ __launch_bounds__(256) void transpose_ct(const float* __restrict__ X,
                                                    u16* __restrict__ Xt) {
    __shared__ u16 tile[64][65];
    const int tid = threadIdx.x;
    const int t0 = blockIdx.x * 64;
    const int c0 = blockIdx.y * 64;
#pragma unroll
    for (int i = 0; i < 16; ++i) {
        int idx = tid + i * 256;
        int r = idx >> 6, cc = idx & 63;
        tile[r][cc] = f2bf(X[(size_t)(c0 + r) * 4096 + t0 + cc]);
    }
    __syncthreads();
#pragma unroll
    for (int i = 0; i < 16; ++i) {
        int idx = tid + i * 256;
        int tr = idx >> 6, cc = idx & 63;
        Xt[(size_t)(t0 + tr) * 512 + c0 + cc] = tile[cc][tr];
    }
}

// ---------------------------------------------------------------------------
// GEMM: val[o][t] = (sum_i W[o][i] * Bt[t][i] + bias[o]) * scale
// W: 512x512 bf16 row-major.  Bt: 4096x512 bf16 token-major.
// mode 0: bf16 out[t*512 + o]            (token-major: Qt, Kt)
// mode 2: fp32 out[o*4096 + t]           (final Y -> d_out)
// mode 3: bf16 out[o*4096 + sigma^-1(t)] (channel-major key-permuted: Vp)
//   within each 32-token group, token u=16b+4q+i stored at 8q+4b+i so that a
//   contiguous A-fragment load reads keys in the order P^T registers hold them.
// ---------------------------------------------------------------------------
__global__ __launch_bounds__(256) void proj_gemm(const u16* __restrict__ W,
                                                 const u16* __restrict__ Bt,
                                                 const float* __restrict__ bias,
                                                 void* __restrict__ outp,
                                                 int mode, float scale) {
    const int tid = threadIdx.x;
    const int w = tid >> 6, lane = tid & 63;
    const int quad = lane >> 4, lm = lane & 15;
    const int t0 = blockIdx.x * 64;
    const int o0 = blockIdx.y * 64;
    const int ow = o0 + w * 16;

    f32x4 acc[4];
#pragma unroll
    for (int nt = 0; nt < 4; ++nt) acc[nt] = (f32x4){0.f, 0.f, 0.f, 0.f};

    const u16* arow = W + (size_t)(ow + lm) * 512 + quad * 8;
    const u16* brow = Bt + (size_t)(t0 + lm) * 512 + quad * 8;

    for (int kc = 0; kc < 16; ++kc) {          // K = 512 = 16 * 32
        bf16x8 a = ldg8(arow + kc * 32);
#pragma unroll
        for (int nt = 0; nt < 4; ++nt) {
            bf16x8 b = ldg8(brow + (size_t)nt * 16 * 512 + kc * 32);
            acc[nt] = MFMA16(a, b, acc[nt]);
        }
    }

    const int ob = ow + quad * 4;
    float bv[4];
#pragma unroll
    for (int r = 0; r < 4; ++r) bv[r] = bias[ob + r];

    if (mode == 0) {                            // token-major bf16
        u16* out = (u16*)outp;
#pragma unroll
        for (int nt = 0; nt < 4; ++nt) {
            u16x4 pk;
#pragma unroll
            for (int r = 0; r < 4; ++r) pk[r] = f2bf((acc[nt][r] + bv[r]) * scale);
            *reinterpret_cast<u16x4*>(out + (size_t)(t0 + nt * 16 + lm) * 512 + ob) = pk;
        }
    } else if (mode == 2) {                     // channel-major fp32 (final output)
        float* out = (float*)outp;
#pragma unroll
        for (int nt = 0; nt < 4; ++nt)
#pragma unroll
            for (int r = 0; r < 4; ++r)
                out[(size_t)(ob + r) * 4096 + t0 + nt * 16 + lm] =
                    (acc[nt][r] + bv[r]) * scale;
    } else {                                    // mode 3: channel-major permuted bf16 (Vp)
        u16* out = (u16*)outp;
#pragma unroll
        for (int nt = 0; nt < 4; ++nt) {
            int g = nt * 16 + lm;
            int col = t0 + (g & 32) + 8 * ((g >> 2) & 3) + 4 * ((g >> 4) & 1) + (g & 3);
#pragma unroll
            for (int r = 0; r < 4; ++r)
                out[(size_t)(ob + r) * 4096 + col] = f2bf((acc[nt][r] + bv[r]) * scale);
        }
    }
}

// ---------------------------------------------------------------------------
// Transposed flash attention, split-K=2.
// Qt/Kt: 4096x512 bf16 token-major. Qt carries scale 0.125*log2(e).
// Vp: 512x4096 bf16 channel-major, sigma-permuted within 32-token groups.
// lqw: 4096 fp32 additive key bias (natural-log domain).
// Ot: 4096x512 bf16 token-major.
// Grid (64 q-tiles, 8 heads), 512 threads = 8 waves.
// Wave w: queries qt0+(w&3)*16 .. +15, key half (w>>2)*2048.
// S^T = K Q^T  (A=K, B=Q): C row=key (quad*4+r), col=query (lm).
// Softmax over keys = over regs + shfl_xor(16,32). P^T C-regs repacked
// (v_perm) ARE the B-operand of O^T = V^T P^T under sigma. No LDS in loop.
// ---------------------------------------------------------------------------
__global__ __launch_bounds__(512, 4) void flash_attn(const u16* __restrict__ Qt,
                                                     const u16* __restrict__ Kt,
                                                     const u16* __restrict__ Vp,
                                                     const float* __restrict__ lqw,
                                                     u16* __restrict__ Ot) {
    __shared__ float Om[4][16][72];   // upper-half O partials [qwave][q][d]
    __shared__ float Ml[4][2][16];    // upper-half m,l per query

    const int tid = threadIdx.x;
    const int w = tid >> 6, lane = tid & 63;
    const int quad = lane >> 4, lm = lane & 15;
    const int qw = w & 3, half = w >> 2;
    const int h = blockIdx.y;
    const int hq = h * 64;
    const int qt0 = blockIdx.x * 64;
    const int q0 = qt0 + qw * 16;
    const int kstart = half * 2048;

    // Q B-fragments (B[k=d][n=q]), d=64 -> two chunks, resident in regs
    const u16* qbase = Qt + (size_t)(q0 + lm) * 512 + hq + quad * 8;
    const bf16x8 bq0 = ldg8(qbase);
    const bf16x8 bq1 = ldg8(qbase + 32);

    f32x4 acc_o[4];
#pragma unroll
    for (int mt = 0; mt < 4; ++mt) acc_o[mt] = (f32x4){0.f, 0.f, 0.f, 0.f};
    float m_st = -1e30f, l_st = 0.f;

    for (int kt0 = kstart; kt0 < kstart + 2048; kt0 += 64) {
        // --- S^T = K Q^T + bias (exp2 domain) ---
        const u16* kbase = Kt + (size_t)(kt0 + lm) * 512 + hq + quad * 8;
        f32x4 st[4];
#pragma unroll
        for (int nt = 0; nt < 4; ++nt) {
            const u16* kb = kbase + (size_t)nt * 16 * 512;
            f32x4 a = (f32x4){0.f, 0.f, 0.f, 0.f};
            a = MFMA16(ldg8(kb), bq0, a);
            a = MFMA16(ldg8(kb + 32), bq1, a);
            float4 lw = *reinterpret_cast<const float4*>(lqw + kt0 + nt * 16 + quad * 4);
            st[nt][0] = fmaf(lw.x, LOG2E, a[0]);
            st[nt][1] = fmaf(lw.y, LOG2E, a[1]);
            st[nt][2] = fmaf(lw.z, LOG2E, a[2]);
            st[nt][3] = fmaf(lw.w, LOG2E, a[3]);
        }

        // --- online softmax: reduce over 16 in-lane values + cross-quad shfl ---
        float mx = st[0][0];
#pragma unroll
        for (int nt = 0; nt < 4; ++nt)
#pragma unroll
            for (int r = 0; r < 4; ++r) mx = fmaxf(mx, st[nt][r]);
        mx = fmaxf(mx, __shfl_xor(mx, 16, 64));
        mx = fmaxf(mx, __shfl_xor(mx, 32, 64));
        float mnew = fmaxf(m_st, mx);
        float alpha = EXP2F(m_st - mnew);
        m_st = mnew;

        float ps = 0.f;
        u32 pk[4][2];
#pragma unroll
        for (int nt = 0; nt < 4; ++nt)
#pragma unroll
            for (int rp = 0; rp < 2; ++rp) {
                float p0 = EXP2F(st[nt][2 * rp] - mnew);
                float p1 = EXP2F(st[nt][2 * rp + 1] - mnew);
                ps += p0 + p1;
                pk[nt][rp] = pack_bf2(p0, p1);
            }
        ps += __shfl_xor(ps, 16, 64);
        ps += __shfl_xor(ps, 32, 64);
        l_st = l_st * alpha + ps;
#pragma unroll
        for (int mt = 0; mt < 4; ++mt)
#pragma unroll
            for (int r = 0; r < 4; ++r) acc_o[mt][r] *= alpha;

        // --- O^T += V^T P^T  (P^T regs are the B-operand; V sigma-permuted) ---
#pragma unroll
        for (int kc = 0; kc < 2; ++kc) {
            union { u32 u[4]; bf16x8 v; } bb;
            bb.u[0] = pk[2 * kc][0];
            bb.u[1] = pk[2 * kc][1];
            bb.u[2] = pk[2 * kc + 1][0];
            bb.u[3] = pk[2 * kc + 1][1];
#pragma unroll
            for (int mt = 0; mt < 4; ++mt) {
                const u16* vb = Vp + (size_t)(hq + mt * 16 + lm) * 4096 + kt0 + kc * 32 + quad * 8;
                acc_o[mt] = MFMA16(ldg8(vb), bb.v, acc_o[mt]);
            }
        }
    }

    // --- split-K merge: upper half -> LDS, lower half combines & stores ---
    if (half == 1) {
#pragma unroll
        for (int mt = 0; mt < 4; ++mt)
            *reinterpret_cast<f32x4*>(&Om[qw][lm][mt * 16 + quad * 4]) = acc_o[mt];
        if (quad == 0) { Ml[qw][0][lm] = m_st; Ml[qw][1][lm] = l_st; }
    }
    __syncthreads();
    if (half == 1) return;

    float m1 = Ml[qw][0][lm], l1 = Ml[qw][1][lm];
    float mf = fmaxf(m_st, m1);
    float a0 = EXP2F(m_st - mf), a1 = EXP2F(m1 - mf);
    float inv = 1.0f / (l_st * a0 + l1 * a1);
    float s0 = a0 * inv, s1 = a1 * inv;
#pragma unroll
    for (int mt = 0; mt < 4; ++mt) {
        f32x4 o1 = *reinterpret_cast<const f32x4*>(&Om[qw][lm][mt * 16 + quad * 4]);
        u16x4 pkv;
#pragma unroll
        for (int r = 0; r < 4; ++r) pkv[r] = f2bf(acc_o[mt][r] * s0 + o1[r] * s1);
        *reinterpret_cast<u16x4*>(Ot + (size_t)(q0 + lm) * 512 + hq + mt * 16 + quad * 4) = pkv;
    }
}

// ---------------------------------------------------------------------------
extern "C" void kernel_launch(void* const* d_in, const int* in_sizes, int n_in,
                              void* d_out, int out_size, void* d_ws, size_t ws_size,
                              hipStream_t stream) {
    (void)in_sizes; (void)n_in; (void)out_size; (void)ws_size;
    const float* X   = (const float*)d_in[0];
    const float* qw  = (const float*)d_in[1];
    const float* qb  = (const float*)d_in[2];
    const float* kw  = (const float*)d_in[3];
    const float* kb  = (const float*)d_in[4];
    const float* vw  = (const float*)d_in[5];
    const float* vb  = (const float*)d_in[6];
    const float* pw  = (const float*)d_in[7];
    const float* pb  = (const float*)d_in[8];
    const float* lqw = (const float*)d_in[9];

    const size_t E = (size_t)4096 * 512;
    const size_t WE = (size_t)512 * 512;
    u16* Xt  = (u16*)d_ws;     // 4 MB
    u16* Qt  = Xt + E;         // 4 MB
    u16* Kt  = Qt + E;         // 4 MB
    u16* Vp  = Kt + E;         // 4 MB (sigma-permuted channel-major V)
    u16* Wq  = Vp + E;
    u16* Wk  = Wq + WE;
    u16* Wv  = Wk + WE;
    u16* Wp  = Wv + WE;
    u16* Ot  = Xt;             // reuse (dead after projections)

    dim3 blk(256);
    transpose_ct<<<dim3(64, 8), blk, 0, stream>>>(X, Xt);
    pack4<<<dim3(256, 4), blk, 0, stream>>>(qw, Wq, kw, Wk, vw, Wv, pw, Wp);
    // Q carries softmax scale AND log2(e) for the exp2-domain softmax
    proj_gemm<<<dim3(64, 8), blk, 0, stream>>>(Wq, Xt, qb, Qt, 0, 0.125f * LOG2E);
    proj_gemm<<<dim3(64, 8), blk, 0, stream>>>(Wk, Xt, kb, Kt, 0, 1.0f);
    proj_gemm<<<dim3(64, 8), blk, 0, stream>>>(Wv, Xt, vb, Vp, 3, 1.0f);
    flash_attn<<<dim3(64, 8), dim3(512), 0, stream>>>(Qt, Kt, Vp, lqw, Ot);
    proj_gemm<<<dim3(64, 8), blk, 0, stream>>>(Wp, Ot, pb, d_out, 2, 1.0f);
}